// Round 10
// baseline (328.642 us; speedup 1.0000x reference)
//
#include <hip/hip_runtime.h>
#include <hip/hip_bf16.h>

// ---- constants -------------------------------------------------------------
#define S_LEN 2048
#define EMB   2048
#define NH    16
#define HD    128

typedef __attribute__((ext_vector_type(8))) __bf16 bf16x8;
typedef __attribute__((ext_vector_type(8))) unsigned short ushort8;
typedef __attribute__((ext_vector_type(4))) unsigned short ushort4v;
typedef __attribute__((ext_vector_type(4))) float  floatx4;

// float -> bf16 bits
__device__ inline unsigned short f2b(float f) {
    __hip_bfloat16 h = __float2bfloat16(f);
    return *reinterpret_cast<unsigned short*>(&h);
}
// bf16 bits -> float (exact)
__device__ inline float b2f(unsigned short u) {
    union { unsigned int i; float f; } c;
    c.i = ((unsigned int)u) << 16;
    return c.f;
}

__device__ inline ushort8 cvt16_lo(const float4& a, const float4& b) {
    ushort8 r;
    r[0] = f2b(a.x); r[1] = f2b(a.y); r[2] = f2b(a.z); r[3] = f2b(a.w);
    r[4] = f2b(b.x); r[5] = f2b(b.y); r[6] = f2b(b.z); r[7] = f2b(b.w);
    return r;
}

// async global->LDS, 16B per lane; LDS dest = wave-uniform base + lane*16
__device__ inline void gll16(const unsigned short* g, unsigned short* l) {
    __builtin_amdgcn_global_load_lds(
        (const __attribute__((address_space(1))) unsigned int*)g,
        (__attribute__((address_space(3))) unsigned int*)l, 16, 0, 0);
}

// ---- bulk fp32 -> bf16 conversion: 5 equal 4M-element segments -------------
__global__ __launch_bounds__(256) void cvt_bf16x5(
    const float* __restrict__ s0, const float* __restrict__ s1,
    const float* __restrict__ s2, const float* __restrict__ s3,
    const float* __restrict__ s4,
    unsigned short* __restrict__ d0, unsigned short* __restrict__ d1,
    unsigned short* __restrict__ d2, unsigned short* __restrict__ d3,
    unsigned short* __restrict__ d4)
{
    const int i = blockIdx.x * 256 + threadIdx.x;  // float4 units
    const float* s; unsigned short* d;
    switch (blockIdx.y) {
        case 0: s = s0; d = d0; break;
        case 1: s = s1; d = d1; break;
        case 2: s = s2; d = d2; break;
        case 3: s = s3; d = d3; break;
        default: s = s4; d = d4; break;
    }
    float4 v = ((const float4*)s)[i];
    ushort4v r;
    r[0] = f2b(v.x); r[1] = f2b(v.y); r[2] = f2b(v.z); r[3] = f2b(v.w);
    ((ushort4v*)d)[i] = r;
}

// =============================================================================
// Async-staged 128x128 GEMM, BK=64 (2 MFMA k-substeps per staging iter).
// LDS per operand: [128][64] shorts = 16 KB, staged as 16 x 1KB chunks of
// 8 rows x 128 B.  XOR column swizzle: phys 16B-chunk p of row r holds logical
// chunk p ^ (r & 7); reads use p = L ^ (r & 7).
// =============================================================================

// ---- fused QKV projection + RoPE / V-transpose epilogues -------------------
// grid (16, 48): by>>4 = widx (0:Q 1:K 2:V), by&15 = head.
__global__ __launch_bounds__(256) void gemm_qkv_async(
    const unsigned short* __restrict__ Ab,
    const unsigned short* __restrict__ Bq, const unsigned short* __restrict__ Bk,
    const unsigned short* __restrict__ Bv,
    __hip_bfloat16* __restrict__ qbuf, __hip_bfloat16* __restrict__ kbuf,
    __hip_bfloat16* __restrict__ vT,
    const float* __restrict__ rc, const float* __restrict__ rs)
{
    __shared__ __align__(16) union {
        struct { unsigned short A[8192]; unsigned short B[8192]; } s; // 16+16 KB
        unsigned short CtV[128][136];   // V transpose buffer
        unsigned short CtR[128][137];   // rope buffer
    } sm;

    const int m0   = blockIdx.x * 128;
    const int by   = blockIdx.y;
    const int widx = by >> 4;
    const int hh   = by & 15;
    const int n0   = hh * 128;
    const unsigned short* Bb = (widx == 0) ? Bq : (widx == 1) ? Bk : Bv;

    const int t    = threadIdx.x;
    const int lane = t & 63;
    const int w    = t >> 6;
    const int l15  = lane & 15;
    const int g4   = lane >> 4;
    const int mw   = (w >> 1) * 64;
    const int nw   = (w & 1) * 64;

    // staging lane mapping: chunk = 8 rows x 64 shorts
    const int rl = lane >> 3;                 // row within chunk 0..7
    const int cl = ((lane & 7) ^ rl) * 8;     // logical col (shorts)

    const floatx4 z = {0.f, 0.f, 0.f, 0.f};
    floatx4 acc[4][4];
    #pragma unroll
    for (int i = 0; i < 4; i++)
        #pragma unroll
        for (int j = 0; j < 4; j++) acc[i][j] = z;

    const int K = EMB;
    for (int k0 = 0; k0 < K; k0 += 64) {
        __syncthreads();   // prior iter's ds_reads done
        #pragma unroll
        for (int c = 0; c < 4; c++) {
            const int ck  = w * 4 + c;           // chunk 0..15
            const int row = ck * 8 + rl;
            gll16(Ab + (size_t)(m0 + row) * K + k0 + cl, &sm.s.A[ck * 512]);
            gll16(Bb + (size_t)(n0 + row) * K + k0 + cl, &sm.s.B[ck * 512]);
        }
        __syncthreads();   // drains vmcnt(0): async copies visible

        #pragma unroll
        for (int s = 0; s < 2; s++) {
            bf16x8 af[4], bg[4];
            #pragma unroll
            for (int i = 0; i < 4; i++)
                af[i] = *(const bf16x8*)&sm.s.A[(mw + i * 16 + l15) * 64
                                                + (((s * 4 + g4) ^ (l15 & 7)) * 8)];
            #pragma unroll
            for (int j = 0; j < 4; j++)
                bg[j] = *(const bf16x8*)&sm.s.B[(nw + j * 16 + l15) * 64
                                                + (((s * 4 + g4) ^ (l15 & 7)) * 8)];
            #pragma unroll
            for (int i = 0; i < 4; i++)
                #pragma unroll
                for (int j = 0; j < 4; j++)
                    acc[i][j] = __builtin_amdgcn_mfma_f32_16x16x32_bf16(af[i], bg[j], acc[i][j], 0, 0, 0);
        }
    }

    // ---- epilogue. C/D layout: col = lane&15, row = (lane>>4)*4 + r --------
    if (widx < 2) {
        // fused RoPE: stage C-tile (dd, s) in LDS, pair dd <-> dd^64
        __syncthreads();
        #pragma unroll
        for (int i = 0; i < 4; i++)
            #pragma unroll
            for (int j = 0; j < 4; j++)
                #pragma unroll
                for (int r = 0; r < 4; r++)
                    sm.CtR[nw + j * 16 + l15][mw + i * 16 + g4 * 4 + r] = f2b(acc[i][j][r]);
        __syncthreads();

        __hip_bfloat16* dst = (widx == 0) ? qbuf : kbuf;
        const int dd  = t & 127;
        const int sl0 = t >> 7;
        #pragma unroll 4
        for (int rep = 0; rep < 64; rep++) {
            const int sl = rep * 2 + sl0;
            const int s  = m0 + sl;
            const float c  = rc[(size_t)s * HD + dd];
            const float sn = rs[(size_t)s * HD + dd];
            const float x0 = b2f(sm.CtR[dd][sl]);
            const float xr = b2f(sm.CtR[dd ^ 64][sl]);
            const float rot = (dd < 64) ? -xr : xr;
            dst[((size_t)hh * S_LEN + s) * HD + dd] = __float2bfloat16(x0 * c + rot * sn);
        }
    } else {
        // V: transpose through LDS, write vT (h,d,s) with b128 stores
        __syncthreads();
        #pragma unroll
        for (int i = 0; i < 4; i++)
            #pragma unroll
            for (int j = 0; j < 4; j++)
                #pragma unroll
                for (int r = 0; r < 4; r++)
                    sm.CtV[nw + j * 16 + l15][mw + i * 16 + g4 * 4 + r] = f2b(acc[i][j][r]);
        __syncthreads();
        const int dd = t >> 1;
        const int ms = (t & 1) * 64;
        __hip_bfloat16* dstv = vT + ((size_t)hh * HD + dd) * S_LEN + m0 + ms;
        #pragma unroll
        for (int c = 0; c < 8; c++)
            *(ushort8*)(dstv + c * 8) = *(const ushort8*)&sm.CtV[dd][ms + c * 8];
    }
}

// ---- output projection, BK=64, split-K x2, fp32 atomicAdd epilogue ---------
// grid (16, 16, 2).  out must be pre-zeroed.
__global__ __launch_bounds__(256) void gemm_wo_async(
    const unsigned short* __restrict__ Ab,
    const unsigned short* __restrict__ Bb,
    float* __restrict__ outMN)
{
    __shared__ __align__(16) struct { unsigned short A[8192]; unsigned short B[8192]; } sm;

    const int m0 = blockIdx.x * 128;
    const int n0 = blockIdx.y * 128;
    const int kz = blockIdx.z;

    const int t    = threadIdx.x;
    const int lane = t & 63;
    const int w    = t >> 6;
    const int l15  = lane & 15;
    const int g4   = lane >> 4;
    const int mw   = (w >> 1) * 64;
    const int nw   = (w & 1) * 64;

    const int rl = lane >> 3;
    const int cl = ((lane & 7) ^ rl) * 8;

    const floatx4 z = {0.f, 0.f, 0.f, 0.f};
    floatx4 acc[4][4];
    #pragma unroll
    for (int i = 0; i < 4; i++)
        #pragma unroll
        for (int j = 0; j < 4; j++) acc[i][j] = z;

    const int K = EMB;
    const int kbeg = kz * (K / 2), kend = kbeg + K / 2;
    for (int k0 = kbeg; k0 < kend; k0 += 64) {
        __syncthreads();
        #pragma unroll
        for (int c = 0; c < 4; c++) {
            const int ck  = w * 4 + c;
            const int row = ck * 8 + rl;
            gll16(Ab + (size_t)(m0 + row) * K + k0 + cl, &sm.A[ck * 512]);
            gll16(Bb + (size_t)(n0 + row) * K + k0 + cl, &sm.B[ck * 512]);
        }
        __syncthreads();

        #pragma unroll
        for (int s = 0; s < 2; s++) {
            bf16x8 af[4], bg[4];
            #pragma unroll
            for (int i = 0; i < 4; i++)
                af[i] = *(const bf16x8*)&sm.A[(mw + i * 16 + l15) * 64
                                              + (((s * 4 + g4) ^ (l15 & 7)) * 8)];
            #pragma unroll
            for (int j = 0; j < 4; j++)
                bg[j] = *(const bf16x8*)&sm.B[(nw + j * 16 + l15) * 64
                                              + (((s * 4 + g4) ^ (l15 & 7)) * 8)];
            #pragma unroll
            for (int i = 0; i < 4; i++)
                #pragma unroll
                for (int j = 0; j < 4; j++)
                    acc[i][j] = __builtin_amdgcn_mfma_f32_16x16x32_bf16(af[i], bg[j], acc[i][j], 0, 0, 0);
        }
    }

    #pragma unroll
    for (int i = 0; i < 4; i++)
        #pragma unroll
        for (int j = 0; j < 4; j++)
            #pragma unroll
            for (int r = 0; r < 4; r++) {
                const int row = m0 + mw + i * 16 + g4 * 4 + r;
                const int col = n0 + nw + j * 16 + l15;
                atomicAdd(&outMN[(size_t)row * EMB + col], acc[i][j][r]);
            }
}

// ---- flash attention v7: split-K (z=2), static max, additive partials ------
// grid (32, 16, 2).  Block handles q-tile bx, head h, K-chunk z.
// Writes bf16 partial O (undivided) and fp32 partial l.
__global__ __launch_bounds__(256) void flash_attn_sk(
    const __hip_bfloat16* __restrict__ qb, const __hip_bfloat16* __restrict__ kb,
    const __hip_bfloat16* __restrict__ vT,
    unsigned short* __restrict__ O0, unsigned short* __restrict__ O1,
    float* __restrict__ lp0, float* __restrict__ lp1)
{
    __shared__ __align__(16) unsigned short Ks[64][136];
    __shared__ __align__(16) unsigned short Vs[128][72];
    __shared__ __align__(16) unsigned short Ps[4][16][72];

    const int bx = (gridDim.x - 1) - blockIdx.x;  // long blocks first
    const int q0 = bx * 64;
    const int h  = blockIdx.y;
    const int zz = blockIdx.z;
    const int T  = bx + 1;             // total 64-key tiles for this q-block
    const int Th = (T + 1) >> 1;
    const int t0 = (zz == 0) ? 0 : Th;
    const int t1 = (zz == 0) ? Th : T;

    const int t    = threadIdx.x;
    const int lane = t & 63;
    const int w    = t >> 6;
    const size_t hb  = (size_t)h * S_LEN;
    const size_t hbT = (size_t)h * HD;

    const int l15 = lane & 15;
    const int g4  = lane >> 4;
    const int koff = g4 * 8;

    const int kr = t >> 2;
    const int kc = (t & 3) * 32;
    const int vr = t >> 1;
    const int vc = (t & 1) * 32;

    bf16x8 qf[4];
    const __hip_bfloat16* qrow = qb + (hb + q0 + w * 16 + l15) * HD;
    #pragma unroll
    for (int kk = 0; kk < 4; kk++)
        qf[kk] = *(const bf16x8*)(qrow + kk * 32 + koff);

    const floatx4 z = {0.f, 0.f, 0.f, 0.f};
    floatx4 O[8] = {z, z, z, z, z, z, z, z};
    float lpart[4] = {0.f, 0.f, 0.f, 0.f};

    const float scale = 0.08838834764831845f;  // 1/sqrt(128)

    ushort8 krg[4], vrg[4];
    if (t0 < t1) {
        const __hip_bfloat16* kg = kb + (hb + t0 * 64 + kr) * HD + kc;
        const __hip_bfloat16* vg = vT + (hbT + vr) * S_LEN + t0 * 64 + vc;
        #pragma unroll
        for (int c = 0; c < 4; c++) krg[c] = *(const ushort8*)(kg + c * 8);
        #pragma unroll
        for (int c = 0; c < 4; c++) vrg[c] = *(const ushort8*)(vg + c * 8);
    }

    for (int ti = t0; ti < t1; ti++) {
        const int jb0 = ti * 64;
        __syncthreads();
        #pragma unroll
        for (int c = 0; c < 4; c++) *(ushort8*)&Ks[kr][kc + c * 8] = krg[c];
        #pragma unroll
        for (int c = 0; c < 4; c++) *(ushort8*)&Vs[vr][vc + c * 8] = vrg[c];
        __syncthreads();

        if (ti + 1 < t1) {
            const __hip_bfloat16* kg = kb + (hb + jb0 + 64 + kr) * HD + kc;
            const __hip_bfloat16* vg = vT + (hbT + vr) * S_LEN + jb0 + 64 + vc;
            #pragma unroll
            for (int c = 0; c < 4; c++) krg[c] = *(const ushort8*)(kg + c * 8);
            #pragma unroll
            for (int c = 0; c < 4; c++) vrg[c] = *(const ushort8*)(vg + c * 8);
        }

        floatx4 sc[4];
        #pragma unroll
        for (int jb = 0; jb < 4; jb++) {
            floatx4 acc = z;
            #pragma unroll
            for (int kk = 0; kk < 4; kk++) {
                bf16x8 kf = *(const bf16x8*)&Ks[jb * 16 + l15][kk * 32 + koff];
                acc = __builtin_amdgcn_mfma_f32_16x16x32_bf16(qf[kk], kf, acc, 0, 0, 0);
            }
            sc[jb] = acc;
        }

        const bool diag = (jb0 == q0);
        #pragma unroll
        for (int jb = 0; jb < 4; jb++)
            #pragma unroll
            for (int r = 0; r < 4; r++) {
                float s = sc[jb][r] * scale;
                if (diag && (jb * 16 + l15) > (w * 16 + g4 * 4 + r)) s = -1e30f;
                float p = __expf(s - 6.0f);
                sc[jb][r] = p;
                lpart[r] += p;
            }

        #pragma unroll
        for (int jb = 0; jb < 4; jb++)
            #pragma unroll
            for (int r = 0; r < 4; r++)
                Ps[w][g4 * 4 + r][jb * 16 + l15] = f2b(sc[jb][r]);

        #pragma unroll
        for (int half = 0; half < 2; half++) {
            bf16x8 af = *(const bf16x8*)&Ps[w][l15][half * 32 + koff];
            #pragma unroll
            for (int db = 0; db < 8; db++) {
                bf16x8 bf = *(const bf16x8*)&Vs[db * 16 + l15][half * 32 + koff];
                O[db] = __builtin_amdgcn_mfma_f32_16x16x32_bf16(af, bf, O[db], 0, 0, 0);
            }
        }
    }

    // ---- partial-l: reduce across 16-lane group, write once per row
    unsigned short* Oz = zz ? O1 : O0;
    float*          lz = zz ? lp1 : lp0;
    #pragma unroll
    for (int r = 0; r < 4; r++) {
        float s = lpart[r];
        #pragma unroll
        for (int o = 1; o < 16; o <<= 1) s += __shfl_xor(s, o, 64);
        if (l15 == 0)
            lz[(h << 11) + q0 + w * 16 + g4 * 4 + r] = s;
    }

    // ---- partial-O (undivided), (s, h*HD+d) bf16
    #pragma unroll
    for (int db = 0; db < 8; db++)
        #pragma unroll
        for (int r = 0; r < 4; r++) {
            const int row = q0 + w * 16 + g4 * 4 + r;
            const int col = h * HD + db * 16 + l15;
            Oz[(size_t)row * EMB + col] = f2b(O[db][r]);
        }
}

// ---- combine: attnb = (O0 + O1) / (l0 + l1) --------------------------------
__global__ __launch_bounds__(256) void attn_combine(
    const unsigned short* __restrict__ O0, const unsigned short* __restrict__ O1,
    const float* __restrict__ lp0, const float* __restrict__ lp1,
    __hip_bfloat16* __restrict__ attnb)
{
    const int idx  = blockIdx.x * 256 + threadIdx.x;  // 8-elem units
    const int base = idx * 8;
    const int s    = base >> 11;
    const int col  = base & 2047;
    const int h    = col >> 7;
    const float l  = lp0[(h << 11) + s] + lp1[(h << 11) + s];
    const float inv = 1.f / l;
    ushort8 a = *(const ushort8*)(O0 + base);
    ushort8 b = *(const ushort8*)(O1 + base);
    ushort8 r;
    #pragma unroll
    for (int e = 0; e < 8; e++)
        r[e] = f2b((b2f(a[e]) + b2f(b[e])) * inv);
    *(ushort8*)((unsigned short*)attnb + base) = r;
}

// ---- fallback (ws too small): fp32-input 128-tile GEMM, sync staging -------
template <int MODE>
__global__ __launch_bounds__(256) void gemm128f(
    const void* __restrict__ Av,
    const void* __restrict__ B0v, const void* __restrict__ B1v,
    const void* __restrict__ B2v,
    float* __restrict__ outMN,
    __hip_bfloat16* __restrict__ qbuf, __hip_bfloat16* __restrict__ kbuf,
    __hip_bfloat16* __restrict__ vT,
    const float* __restrict__ rc, const float* __restrict__ rs)
{
    __shared__ union {
        struct { unsigned short A[128][40]; unsigned short B[128][40]; } s;
        unsigned short CtV[128][136];
        unsigned short CtR[128][137];
    } sm;

    const int m0 = blockIdx.x * 128;
    const int by = blockIdx.y;

    int widx = 0, hh = 0, n0 = 0;
    const void* Bv;
    if (MODE == 1) {
        widx = by >> 4; hh = by & 15; n0 = hh * 128;
        Bv = (widx == 0) ? B0v : (widx == 1) ? B1v : B2v;
    } else { n0 = by * 128; Bv = B0v; }

    const int t = threadIdx.x, lane = t & 63, w = t >> 6;
    const int l15 = lane & 15, g4 = lane >> 4, koff = g4 * 8;
    const int mw = (w >> 1) * 64, nw = (w & 1) * 64;
    const int srow = t >> 1, scol = (t & 1) * 16;

    const floatx4 z = {0.f, 0.f, 0.f, 0.f};
    floatx4 acc[4][4];
    #pragma unroll
    for (int i = 0; i < 4; i++)
        #pragma unroll
        for (int j = 0; j < 4; j++) acc[i][j] = z;

    const int K = EMB;
    for (int k0 = 0; k0 < K; k0 += 32) {
        ushort8 a0, a1, b0, b1;
        if (MODE == 0) {
            const unsigned short* Ab = (const unsigned short*)Av;
            a0 = *(const ushort8*)(Ab + (size_t)(m0 + srow) * K + k0 + scol);
            a1 = *(const ushort8*)(Ab + (size_t)(m0 + srow) * K + k0 + scol + 8);
        } else {
            const float* Af = (const float*)Av;
            const float* ap = Af + (size_t)(m0 + srow) * K + k0 + scol;
            a0 = cvt16_lo(*(const float4*)(ap),     *(const float4*)(ap + 4));
            a1 = cvt16_lo(*(const float4*)(ap + 8), *(const float4*)(ap + 12));
        }
        {
            const float* Bf = (const float*)Bv;
            const float* bp = Bf + (size_t)(n0 + srow) * K + k0 + scol;
            b0 = cvt16_lo(*(const float4*)(bp),     *(const float4*)(bp + 4));
            b1 = cvt16_lo(*(const float4*)(bp + 8), *(const float4*)(bp + 12));
        }
        __syncthreads();
        *(ushort8*)&sm.s.A[srow][scol]     = a0;
        *(ushort8*)&sm.s.A[srow][scol + 8] = a1;
        *(ushort8*)&sm.s.B[srow][scol]     = b0;
        *(ushort8*)&sm.s.B[srow][scol + 8] = b1;
        __syncthreads();

        bf16x8 af[4], bg[4];
        #pragma unroll
        for (int i = 0; i < 4; i++)
            af[i] = *(const bf16x8*)&sm.s.A[mw + i * 16 + l15][koff];
        #pragma unroll
        for (int j = 0; j < 4; j++)
            bg[j] = *(const bf16x8*)&sm.s.B[nw + j * 16 + l15][koff];
        #pragma unroll
        for (int i = 0; i < 4; i++)
            #pragma unroll
            for (int j = 0; j < 4; j++)
                acc[i][j] = __builtin_amdgcn_mfma_f32_16x16x32_bf16(af[i], bg[j], acc[i][j], 0, 0, 0);
    }

    if (MODE == 0) {
        #pragma unroll
        for (int i = 0; i < 4; i++)
            #pragma unroll
            for (int j = 0; j < 4; j++)
                #pragma unroll
                for (int r = 0; r < 4; r++) {
                    int row = m0 + mw + i * 16 + g4 * 4 + r;
                    int col = n0 + nw + j * 16 + l15;
                    outMN[(size_t)row * EMB + col] = acc[i][j][r];
                }
    } else if (widx < 2) {
        __syncthreads();
        #pragma unroll
        for (int i = 0; i < 4; i++)
            #pragma unroll
            for (int j = 0; j < 4; j++)
                #pragma unroll
                for (int r = 0; r < 4; r++)
                    sm.CtR[nw + j * 16 + l15][mw + i * 16 + g4 * 4 + r] = f2b(acc[i][j][r]);
        __syncthreads();
        __hip_bfloat16* dst = (widx == 0) ? qbuf : kbuf;
        const int dd = t & 127, sl0 = t >> 7;
        #pragma unroll 4
        for (int rep = 0; rep < 64; rep++) {
            const int sl = rep * 2 + sl0;
            const int s  = m0 + sl;
            const float c  = rc[(size_t)s * HD + dd];
            const float sn = rs[(size_t)s * HD + dd];
            const float x0 = b2f(sm.CtR[dd][sl]);
            const float xr = b2f(sm.CtR[dd ^ 64][sl]);
            const float rot = (dd < 64) ? -xr : xr;
            dst[((size_t)hh * S_LEN + s) * HD + dd] = __float2bfloat16(x0 * c + rot * sn);
        }
    } else {
        __syncthreads();
        #pragma unroll
        for (int i = 0; i < 4; i++)
            #pragma unroll
            for (int j = 0; j < 4; j++)
                #pragma unroll
                for (int r = 0; r < 4; r++)
                    sm.CtV[nw + j * 16 + l15][mw + i * 16 + g4 * 4 + r] = f2b(acc[i][j][r]);
        __syncthreads();
        const int dd = t >> 1, ms = (t & 1) * 64;
        __hip_bfloat16* dstv = vT + ((size_t)hh * HD + dd) * S_LEN + m0 + ms;
        #pragma unroll
        for (int c = 0; c < 8; c++)
            *(ushort8*)(dstv + c * 8) = *(const ushort8*)&sm.CtV[dd][ms + c * 8];
    }
}

// ---- fallback flash (non-split), as in R8 ----------------------------------
__global__ __launch_bounds__(256) void flash_attn(
    const __hip_bfloat16* __restrict__ qb, const __hip_bfloat16* __restrict__ kb,
    const __hip_bfloat16* __restrict__ vT, __hip_bfloat16* __restrict__ attnb)
{
    __shared__ __align__(16) unsigned short Ks[64][136];
    __shared__ __align__(16) unsigned short Vs[128][72];
    __shared__ __align__(16) unsigned short Ps[4][16][72];

    const int bx = (gridDim.x - 1) - blockIdx.x;
    const int q0 = bx * 64;
    const int h  = blockIdx.y;
    const int t    = threadIdx.x;
    const int lane = t & 63;
    const int w    = t >> 6;
    const size_t hb  = (size_t)h * S_LEN;
    const size_t hbT = (size_t)h * HD;

    const int l15 = lane & 15;
    const int g4  = lane >> 4;
    const int koff = g4 * 8;

    const int kr = t >> 2;
    const int kc = (t & 3) * 32;
    const int vr = t >> 1;
    const int vc = (t & 1) * 32;

    bf16x8 qf[4];
    const __hip_bfloat16* qrow = qb + (hb + q0 + w * 16 + l15) * HD;
    #pragma unroll
    for (int kk = 0; kk < 4; kk++)
        qf[kk] = *(const bf16x8*)(qrow + kk * 32 + koff);

    const floatx4 z = {0.f, 0.f, 0.f, 0.f};
    floatx4 O[8] = {z, z, z, z, z, z, z, z};
    float lpart[4] = {0.f, 0.f, 0.f, 0.f};

    const float scale = 0.08838834764831845f;

    ushort8 krg[4], vrg[4];
    {
        const __hip_bfloat16* kg = kb + (hb + kr) * HD + kc;
        const __hip_bfloat16* vg = vT + (hbT + vr) * S_LEN + vc;
        #pragma unroll
        for (int c = 0; c < 4; c++) krg[c] = *(const ushort8*)(kg + c * 8);
        #pragma unroll
        for (int c = 0; c < 4; c++) vrg[c] = *(const ushort8*)(vg + c * 8);
    }

    for (int jb0 = 0; jb0 <= q0; jb0 += 64) {
        __syncthreads();
        #pragma unroll
        for (int c = 0; c < 4; c++) *(ushort8*)&Ks[kr][kc + c * 8] = krg[c];
        #pragma unroll
        for (int c = 0; c < 4; c++) *(ushort8*)&Vs[vr][vc + c * 8] = vrg[c];
        __syncthreads();

        if (jb0 + 64 <= q0) {
            const __hip_bfloat16* kg = kb + (hb + jb0 + 64 + kr) * HD + kc;
            const __hip_bfloat16* vg = vT + (hbT + vr) * S_LEN + jb0 + 64 + vc;
            #pragma unroll
            for (int c = 0; c < 4; c++) krg[c] = *(const ushort8*)(kg + c * 8);
            #pragma unroll
            for (int c = 0; c < 4; c++) vrg[c] = *(const ushort8*)(vg + c * 8);
        }

        floatx4 sc[4];
        #pragma unroll
        for (int jb = 0; jb < 4; jb++) {
            floatx4 acc = z;
            #pragma unroll
            for (int kk = 0; kk < 4; kk++) {
                bf16x8 kf = *(const bf16x8*)&Ks[jb * 16 + l15][kk * 32 + koff];
                acc = __builtin_amdgcn_mfma_f32_16x16x32_bf16(qf[kk], kf, acc, 0, 0, 0);
            }
            sc[jb] = acc;
        }

        const bool diag = (jb0 == q0);
        #pragma unroll
        for (int jb = 0; jb < 4; jb++)
            #pragma unroll
            for (int r = 0; r < 4; r++) {
                float s = sc[jb][r] * scale;
                if (diag && (jb * 16 + l15) > (w * 16 + g4 * 4 + r)) s = -1e30f;
                float p = __expf(s - 6.0f);
                sc[jb][r] = p;
                lpart[r] += p;
            }

        #pragma unroll
        for (int jb = 0; jb < 4; jb++)
            #pragma unroll
            for (int r = 0; r < 4; r++)
                Ps[w][g4 * 4 + r][jb * 16 + l15] = f2b(sc[jb][r]);

        #pragma unroll
        for (int half = 0; half < 2; half++) {
            bf16x8 af = *(const bf16x8*)&Ps[w][l15][half * 32 + koff];
            #pragma unroll
            for (int db = 0; db < 8; db++) {
                bf16x8 bf = *(const bf16x8*)&Vs[db * 16 + l15][half * 32 + koff];
                O[db] = __builtin_amdgcn_mfma_f32_16x16x32_bf16(af, bf, O[db], 0, 0, 0);
            }
        }
    }

    float inv[4];
    #pragma unroll
    for (int r = 0; r < 4; r++) {
        float s = lpart[r];
        #pragma unroll
        for (int o = 1; o < 16; o <<= 1) s += __shfl_xor(s, o, 64);
        inv[r] = 1.f / s;
    }

    #pragma unroll
    for (int db = 0; db < 8; db++)
        #pragma unroll
        for (int r = 0; r < 4; r++) {
            const int row = q0 + w * 16 + g4 * 4 + r;
            const int col = h * HD + db * 16 + l15;
            attnb[(size_t)row * EMB + col] = __float2bfloat16(O[db][r] * inv[r]);
        }
}

// ---- launch ---------------------------------------------------------------
extern "C" void kernel_launch(void* const* d_in, const int* in_sizes, int n_in,
                              void* d_out, int out_size, void* d_ws, size_t ws_size,
                              hipStream_t stream) {
    const float* x  = (const float*)d_in[0];
    const float* rc = (const float*)d_in[1];
    const float* rs = (const float*)d_in[2];
    const float* Wq = (const float*)d_in[3];
    const float* Wk = (const float*)d_in[4];
    const float* Wv = (const float*)d_in[5];
    const float* Wo = (const float*)d_in[6];
    float* out = (float*)d_out;

    const size_t MB = 1u << 20;
    char* ws = (char*)d_ws;
    __hip_bfloat16* qbuf  = (__hip_bfloat16*)(ws);            // (h,s,d)  8 MB
    __hip_bfloat16* kbuf  = (__hip_bfloat16*)(ws +  8 * MB);  // (h,s,d)  8 MB
    __hip_bfloat16* vTbuf = (__hip_bfloat16*)(ws + 16 * MB);  // (h,d,s)  8 MB
    __hip_bfloat16* attnb = (__hip_bfloat16*)(ws + 24 * MB);  // (s,h*d)  8 MB

    const bool pre = (ws_size >= 72 * MB);

    if (pre) {
        unsigned short* xb  = (unsigned short*)(ws + 32 * MB);
        unsigned short* wqb = (unsigned short*)(ws + 40 * MB);
        unsigned short* wkb = (unsigned short*)(ws + 48 * MB);
        unsigned short* wvb = (unsigned short*)(ws + 56 * MB);
        unsigned short* wob = (unsigned short*)(ws + 64 * MB);
        // regions reused AFTER the QKV GEMM (xb/wqb/wkb are dead by then):
        unsigned short* Op0 = xb;                                // 8 MB
        unsigned short* Op1 = wqb;                               // 8 MB
        float*          lp0 = (float*)wkb;                       // 128 KB
        float*          lp1 = (float*)(ws + 48 * MB + 256 * 1024);

        // zero the fp32 output for the split-K atomic accumulation
        hipMemsetAsync(out, 0, (size_t)S_LEN * EMB * sizeof(float), stream);

        hipLaunchKernelGGL(cvt_bf16x5, dim3(4096, 5), dim3(256), 0, stream,
                           x, Wq, Wk, Wv, Wo, xb, wqb, wkb, wvb, wob);

        hipLaunchKernelGGL(gemm_qkv_async, dim3(16, 48), dim3(256), 0, stream,
                           xb, wqb, wkb, wvb, qbuf, kbuf, vTbuf, rc, rs);

        hipLaunchKernelGGL(flash_attn_sk, dim3(S_LEN / 64, NH, 2), dim3(256), 0, stream,
                           qbuf, kbuf, vTbuf, Op0, Op1, lp0, lp1);

        hipLaunchKernelGGL(attn_combine, dim3(2048), dim3(256), 0, stream,
                           Op0, Op1, lp0, lp1, attnb);

        hipLaunchKernelGGL(gemm_wo_async, dim3(16, 16, 2), dim3(256), 0, stream,
                           (const unsigned short*)attnb, wob, out);
    } else {
        hipLaunchKernelGGL((gemm128f<1>), dim3(16, 48), dim3(256), 0, stream,
                           (const void*)x, (const void*)Wq, (const void*)Wk,
                           (const void*)Wv, (float*)nullptr,
                           qbuf, kbuf, vTbuf, rc, rs);

        hipLaunchKernelGGL(flash_attn, dim3(S_LEN / 64, NH), dim3(256), 0, stream,
                           qbuf, kbuf, vTbuf, attnb);

        hipLaunchKernelGGL((gemm128f<0>), dim3(16, 16), dim3(256), 0, stream,
                           (const void*)attnb, (const void*)Wo, (const void*)nullptr,
                           (const void*)nullptr, out,
                           (__hip_bfloat16*)nullptr, (__hip_bfloat16*)nullptr,
                           (__hip_bfloat16*)nullptr, rc, rs);
    }
}

// Round 11
// 293.768 us; speedup vs baseline: 1.1187x; 1.1187x over previous
//
#include <hip/hip_runtime.h>
#include <hip/hip_bf16.h>

// ---- constants -------------------------------------------------------------
#define S_LEN 2048
#define EMB   2048
#define NH    16
#define HD    128

typedef __attribute__((ext_vector_type(8))) __bf16 bf16x8;
typedef __attribute__((ext_vector_type(8))) unsigned short ushort8;
typedef __attribute__((ext_vector_type(4))) unsigned short ushort4v;
typedef __attribute__((ext_vector_type(4))) float  floatx4;

// float -> bf16 bits
__device__ inline unsigned short f2b(float f) {
    __hip_bfloat16 h = __float2bfloat16(f);
    return *reinterpret_cast<unsigned short*>(&h);
}
// bf16 bits -> float (exact)
__device__ inline float b2f(unsigned short u) {
    union { unsigned int i; float f; } c;
    c.i = ((unsigned int)u) << 16;
    return c.f;
}

__device__ inline ushort8 cvt16_lo(const float4& a, const float4& b) {
    ushort8 r;
    r[0] = f2b(a.x); r[1] = f2b(a.y); r[2] = f2b(a.z); r[3] = f2b(a.w);
    r[4] = f2b(b.x); r[5] = f2b(b.y); r[6] = f2b(b.z); r[7] = f2b(b.w);
    return r;
}

// async global->LDS, 16B per lane; LDS dest = wave-uniform base + lane*16
__device__ inline void gll16(const unsigned short* g, unsigned short* l) {
    __builtin_amdgcn_global_load_lds(
        (const __attribute__((address_space(1))) unsigned int*)g,
        (__attribute__((address_space(3))) unsigned int*)l, 16, 0, 0);
}

// ---- bulk fp32 -> bf16 conversion: 5 equal 4M-element segments -------------
__global__ __launch_bounds__(256) void cvt_bf16x5(
    const float* __restrict__ s0, const float* __restrict__ s1,
    const float* __restrict__ s2, const float* __restrict__ s3,
    const float* __restrict__ s4,
    unsigned short* __restrict__ d0, unsigned short* __restrict__ d1,
    unsigned short* __restrict__ d2, unsigned short* __restrict__ d3,
    unsigned short* __restrict__ d4)
{
    const int i = blockIdx.x * 256 + threadIdx.x;  // float4 units
    const float* s; unsigned short* d;
    switch (blockIdx.y) {
        case 0: s = s0; d = d0; break;
        case 1: s = s1; d = d1; break;
        case 2: s = s2; d = d2; break;
        case 3: s = s3; d = d3; break;
        default: s = s4; d = d4; break;
    }
    float4 v = ((const float4*)s)[i];
    ushort4v r;
    r[0] = f2b(v.x); r[1] = f2b(v.y); r[2] = f2b(v.z); r[3] = f2b(v.w);
    ((ushort4v*)d)[i] = r;
}

// =============================================================================
// Async-staged GEMM cores, BK=32 (R9 structure — measured 76 us / 589K confl).
// LDS tile unpadded [rows][32] shorts, staged as 1KB chunks (16 rows x 32
// shorts).  XOR chunk swizzle: phys 16B-chunk p of row r holds logical chunk
// p ^ ((r>>1)&3); fragment reads use pc = g4 ^ ((l15>>1)&3) -> 2-way (free).
// =============================================================================

// ---- fused QKV projection + RoPE / V-transpose epilogues -------------------
// grid (16, 48): by>>4 = widx (0:Q 1:K 2:V), by&15 = head.
__global__ __launch_bounds__(256) void gemm_qkv_async(
    const unsigned short* __restrict__ Ab,
    const unsigned short* __restrict__ Bq, const unsigned short* __restrict__ Bk,
    const unsigned short* __restrict__ Bv,
    __hip_bfloat16* __restrict__ qbuf, __hip_bfloat16* __restrict__ kbuf,
    __hip_bfloat16* __restrict__ vT,
    const float* __restrict__ rc, const float* __restrict__ rs)
{
    __shared__ __align__(16) union {
        struct { unsigned short A[4096]; unsigned short B[4096]; } s; // 8KB+8KB
        unsigned short CtV[128][136];   // V transpose buffer
        unsigned short CtR[128][137];   // rope buffer
    } sm;

    const int m0   = blockIdx.x * 128;
    const int by   = blockIdx.y;
    const int widx = by >> 4;
    const int hh   = by & 15;
    const int n0   = hh * 128;
    const unsigned short* Bb = (widx == 0) ? Bq : (widx == 1) ? Bk : Bv;

    const int t    = threadIdx.x;
    const int lane = t & 63;
    const int w    = t >> 6;
    const int l15  = lane & 15;
    const int g4   = lane >> 4;
    const int mw   = (w >> 1) * 64;
    const int nw   = (w & 1) * 64;

    // staging lane mapping (per 1KB chunk: 16 rows x 32 shorts)
    const int crow = lane >> 2;                       // row within chunk
    const int clog = (lane & 3) ^ ((crow >> 1) & 3);  // logical 16B chunk
    const int pc   = g4 ^ ((l15 >> 1) & 3);           // fragment read swizzle

    const floatx4 z = {0.f, 0.f, 0.f, 0.f};
    floatx4 acc[4][4];
    #pragma unroll
    for (int i = 0; i < 4; i++)
        #pragma unroll
        for (int j = 0; j < 4; j++) acc[i][j] = z;

    const int K = EMB;
    for (int k0 = 0; k0 < K; k0 += 32) {
        __syncthreads();   // prior iter's ds_reads done
        #pragma unroll
        for (int c = 0; c < 2; c++) {
            const int ck  = w * 2 + c;           // chunk 0..7 (16 rows each)
            const int row = ck * 16 + crow;
            gll16(Ab + (size_t)(m0 + row) * K + k0 + clog * 8, &sm.s.A[ck * 512]);
            gll16(Bb + (size_t)(n0 + row) * K + k0 + clog * 8, &sm.s.B[ck * 512]);
        }
        __syncthreads();   // drains vmcnt(0): async copies visible

        bf16x8 af[4], bg[4];
        #pragma unroll
        for (int i = 0; i < 4; i++)
            af[i] = *(const bf16x8*)&sm.s.A[(mw + i * 16 + l15) * 32 + pc * 8];
        #pragma unroll
        for (int j = 0; j < 4; j++)
            bg[j] = *(const bf16x8*)&sm.s.B[(nw + j * 16 + l15) * 32 + pc * 8];

        #pragma unroll
        for (int i = 0; i < 4; i++)
            #pragma unroll
            for (int j = 0; j < 4; j++)
                acc[i][j] = __builtin_amdgcn_mfma_f32_16x16x32_bf16(af[i], bg[j], acc[i][j], 0, 0, 0);
    }

    // ---- epilogue. C/D layout: col = lane&15, row = (lane>>4)*4 + r --------
    if (widx < 2) {
        // fused RoPE: stage C-tile (dd, s) in LDS, pair dd <-> dd^64
        __syncthreads();
        #pragma unroll
        for (int i = 0; i < 4; i++)
            #pragma unroll
            for (int j = 0; j < 4; j++)
                #pragma unroll
                for (int r = 0; r < 4; r++)
                    sm.CtR[nw + j * 16 + l15][mw + i * 16 + g4 * 4 + r] = f2b(acc[i][j][r]);
        __syncthreads();

        __hip_bfloat16* dst = (widx == 0) ? qbuf : kbuf;
        const int dd  = t & 127;
        const int sl0 = t >> 7;
        #pragma unroll 4
        for (int rep = 0; rep < 64; rep++) {
            const int sl = rep * 2 + sl0;
            const int s  = m0 + sl;
            const float c  = rc[(size_t)s * HD + dd];
            const float sn = rs[(size_t)s * HD + dd];
            const float x0 = b2f(sm.CtR[dd][sl]);
            const float xr = b2f(sm.CtR[dd ^ 64][sl]);
            const float rot = (dd < 64) ? -xr : xr;
            dst[((size_t)hh * S_LEN + s) * HD + dd] = __float2bfloat16(x0 * c + rot * sn);
        }
    } else {
        // V: transpose through LDS, write vT (h,d,s) with b128 stores
        __syncthreads();
        #pragma unroll
        for (int i = 0; i < 4; i++)
            #pragma unroll
            for (int j = 0; j < 4; j++)
                #pragma unroll
                for (int r = 0; r < 4; r++)
                    sm.CtV[nw + j * 16 + l15][mw + i * 16 + g4 * 4 + r] = f2b(acc[i][j][r]);
        __syncthreads();
        const int dd = t >> 1;
        const int ms = (t & 1) * 64;
        __hip_bfloat16* dstv = vT + ((size_t)hh * HD + dd) * S_LEN + m0 + ms;
        #pragma unroll
        for (int c = 0; c < 8; c++)
            *(ushort8*)(dstv + c * 8) = *(const ushort8*)&sm.CtV[dd][ms + c * 8];
    }
}

// ---- output projection: 128x64 tiles, grid (16, 32), plain fp32 stores -----
__global__ __launch_bounds__(256) void gemm_wo_async(
    const unsigned short* __restrict__ Ab,
    const unsigned short* __restrict__ Bb,
    float* __restrict__ outMN)
{
    __shared__ __align__(16) struct { unsigned short A[4096]; unsigned short B[2048]; } sm;

    const int m0 = blockIdx.x * 128;
    const int n0 = blockIdx.y * 64;

    const int t    = threadIdx.x;
    const int lane = t & 63;
    const int w    = t >> 6;
    const int l15  = lane & 15;
    const int g4   = lane >> 4;
    const int mw   = (w >> 1) * 64;     // 0 or 64
    const int nw   = (w & 1) * 32;      // 0 or 32

    const int crow = lane >> 2;
    const int clog = (lane & 3) ^ ((crow >> 1) & 3);
    const int pc   = g4 ^ ((l15 >> 1) & 3);

    const floatx4 z = {0.f, 0.f, 0.f, 0.f};
    floatx4 acc[4][2];
    #pragma unroll
    for (int i = 0; i < 4; i++)
        #pragma unroll
        for (int j = 0; j < 2; j++) acc[i][j] = z;

    const int K = EMB;
    for (int k0 = 0; k0 < K; k0 += 32) {
        __syncthreads();
        #pragma unroll
        for (int c = 0; c < 2; c++) {
            const int ck  = w * 2 + c;            // A chunks 0..7
            const int row = ck * 16 + crow;
            gll16(Ab + (size_t)(m0 + row) * K + k0 + clog * 8, &sm.A[ck * 512]);
        }
        {
            const int row = w * 16 + crow;        // B chunks 0..3 (one per wave)
            gll16(Bb + (size_t)(n0 + row) * K + k0 + clog * 8, &sm.B[w * 512]);
        }
        __syncthreads();

        bf16x8 af[4], bg[2];
        #pragma unroll
        for (int i = 0; i < 4; i++)
            af[i] = *(const bf16x8*)&sm.A[(mw + i * 16 + l15) * 32 + pc * 8];
        #pragma unroll
        for (int j = 0; j < 2; j++)
            bg[j] = *(const bf16x8*)&sm.B[(nw + j * 16 + l15) * 32 + pc * 8];

        #pragma unroll
        for (int i = 0; i < 4; i++)
            #pragma unroll
            for (int j = 0; j < 2; j++)
                acc[i][j] = __builtin_amdgcn_mfma_f32_16x16x32_bf16(af[i], bg[j], acc[i][j], 0, 0, 0);
    }

    #pragma unroll
    for (int i = 0; i < 4; i++)
        #pragma unroll
        for (int j = 0; j < 2; j++)
            #pragma unroll
            for (int r = 0; r < 4; r++) {
                const int row = m0 + mw + i * 16 + g4 * 4 + r;
                const int col = n0 + nw + j * 16 + l15;
                outMN[(size_t)row * EMB + col] = acc[i][j][r];
            }
}

// ---- flash attention: split-K (z=2), static max, additive partials ---------
// grid (32, 16, 2).  Writes bf16 partial O (undivided) and fp32 partial l.
__global__ __launch_bounds__(256) void flash_attn_sk(
    const __hip_bfloat16* __restrict__ qb, const __hip_bfloat16* __restrict__ kb,
    const __hip_bfloat16* __restrict__ vT,
    unsigned short* __restrict__ O0, unsigned short* __restrict__ O1,
    float* __restrict__ lp0, float* __restrict__ lp1)
{
    __shared__ __align__(16) unsigned short Ks[64][136];
    __shared__ __align__(16) unsigned short Vs[128][72];
    __shared__ __align__(16) unsigned short Ps[4][16][72];

    const int bx = (gridDim.x - 1) - blockIdx.x;  // long blocks first
    const int q0 = bx * 64;
    const int h  = blockIdx.y;
    const int zz = blockIdx.z;
    const int T  = bx + 1;             // total 64-key tiles for this q-block
    const int Th = (T + 1) >> 1;
    const int t0 = (zz == 0) ? 0 : Th;
    const int t1 = (zz == 0) ? Th : T;

    const int t    = threadIdx.x;
    const int lane = t & 63;
    const int w    = t >> 6;
    const size_t hb  = (size_t)h * S_LEN;
    const size_t hbT = (size_t)h * HD;

    const int l15 = lane & 15;
    const int g4  = lane >> 4;
    const int koff = g4 * 8;

    const int kr = t >> 2;
    const int kc = (t & 3) * 32;
    const int vr = t >> 1;
    const int vc = (t & 1) * 32;

    bf16x8 qf[4];
    const __hip_bfloat16* qrow = qb + (hb + q0 + w * 16 + l15) * HD;
    #pragma unroll
    for (int kk = 0; kk < 4; kk++)
        qf[kk] = *(const bf16x8*)(qrow + kk * 32 + koff);

    const floatx4 z = {0.f, 0.f, 0.f, 0.f};
    floatx4 O[8] = {z, z, z, z, z, z, z, z};
    float lpart[4] = {0.f, 0.f, 0.f, 0.f};

    const float scale = 0.08838834764831845f;  // 1/sqrt(128)

    ushort8 krg[4], vrg[4];
    if (t0 < t1) {
        const __hip_bfloat16* kg = kb + (hb + t0 * 64 + kr) * HD + kc;
        const __hip_bfloat16* vg = vT + (hbT + vr) * S_LEN + t0 * 64 + vc;
        #pragma unroll
        for (int c = 0; c < 4; c++) krg[c] = *(const ushort8*)(kg + c * 8);
        #pragma unroll
        for (int c = 0; c < 4; c++) vrg[c] = *(const ushort8*)(vg + c * 8);
    }

    for (int ti = t0; ti < t1; ti++) {
        const int jb0 = ti * 64;
        __syncthreads();
        #pragma unroll
        for (int c = 0; c < 4; c++) *(ushort8*)&Ks[kr][kc + c * 8] = krg[c];
        #pragma unroll
        for (int c = 0; c < 4; c++) *(ushort8*)&Vs[vr][vc + c * 8] = vrg[c];
        __syncthreads();

        if (ti + 1 < t1) {
            const __hip_bfloat16* kg = kb + (hb + jb0 + 64 + kr) * HD + kc;
            const __hip_bfloat16* vg = vT + (hbT + vr) * S_LEN + jb0 + 64 + vc;
            #pragma unroll
            for (int c = 0; c < 4; c++) krg[c] = *(const ushort8*)(kg + c * 8);
            #pragma unroll
            for (int c = 0; c < 4; c++) vrg[c] = *(const ushort8*)(vg + c * 8);
        }

        floatx4 sc[4];
        #pragma unroll
        for (int jb = 0; jb < 4; jb++) {
            floatx4 acc = z;
            #pragma unroll
            for (int kk = 0; kk < 4; kk++) {
                bf16x8 kf = *(const bf16x8*)&Ks[jb * 16 + l15][kk * 32 + koff];
                acc = __builtin_amdgcn_mfma_f32_16x16x32_bf16(qf[kk], kf, acc, 0, 0, 0);
            }
            sc[jb] = acc;
        }

        const bool diag = (jb0 == q0);
        #pragma unroll
        for (int jb = 0; jb < 4; jb++)
            #pragma unroll
            for (int r = 0; r < 4; r++) {
                float s = sc[jb][r] * scale;
                if (diag && (jb * 16 + l15) > (w * 16 + g4 * 4 + r)) s = -1e30f;
                float p = __expf(s - 6.0f);
                sc[jb][r] = p;
                lpart[r] += p;
            }

        #pragma unroll
        for (int jb = 0; jb < 4; jb++)
            #pragma unroll
            for (int r = 0; r < 4; r++)
                Ps[w][g4 * 4 + r][jb * 16 + l15] = f2b(sc[jb][r]);

        #pragma unroll
        for (int half = 0; half < 2; half++) {
            bf16x8 af = *(const bf16x8*)&Ps[w][l15][half * 32 + koff];
            #pragma unroll
            for (int db = 0; db < 8; db++) {
                bf16x8 bf = *(const bf16x8*)&Vs[db * 16 + l15][half * 32 + koff];
                O[db] = __builtin_amdgcn_mfma_f32_16x16x32_bf16(af, bf, O[db], 0, 0, 0);
            }
        }
    }

    // ---- partial-l: reduce across 16-lane group, write once per row
    unsigned short* Oz = zz ? O1 : O0;
    float*          lz = zz ? lp1 : lp0;
    #pragma unroll
    for (int r = 0; r < 4; r++) {
        float s = lpart[r];
        #pragma unroll
        for (int o = 1; o < 16; o <<= 1) s += __shfl_xor(s, o, 64);
        if (l15 == 0)
            lz[(h << 11) + q0 + w * 16 + g4 * 4 + r] = s;
    }

    // ---- partial-O (undivided), (s, h*HD+d) bf16
    #pragma unroll
    for (int db = 0; db < 8; db++)
        #pragma unroll
        for (int r = 0; r < 4; r++) {
            const int row = q0 + w * 16 + g4 * 4 + r;
            const int col = h * HD + db * 16 + l15;
            Oz[(size_t)row * EMB + col] = f2b(O[db][r]);
        }
}

// ---- combine: attnb = (O0 + O1) / (l0 + l1) --------------------------------
__global__ __launch_bounds__(256) void attn_combine(
    const unsigned short* __restrict__ O0, const unsigned short* __restrict__ O1,
    const float* __restrict__ lp0, const float* __restrict__ lp1,
    __hip_bfloat16* __restrict__ attnb)
{
    const int idx  = blockIdx.x * 256 + threadIdx.x;  // 8-elem units
    const int base = idx * 8;
    const int s    = base >> 11;
    const int col  = base & 2047;
    const int h    = col >> 7;
    const float l  = lp0[(h << 11) + s] + lp1[(h << 11) + s];
    const float inv = 1.f / l;
    ushort8 a = *(const ushort8*)(O0 + base);
    ushort8 b = *(const ushort8*)(O1 + base);
    ushort8 r;
    #pragma unroll
    for (int e = 0; e < 8; e++)
        r[e] = f2b((b2f(a[e]) + b2f(b[e])) * inv);
    *(ushort8*)((unsigned short*)attnb + base) = r;
}

// ---- fallback (ws too small): fp32-input 128-tile GEMM, sync staging -------
template <int MODE>
__global__ __launch_bounds__(256) void gemm128f(
    const void* __restrict__ Av,
    const void* __restrict__ B0v, const void* __restrict__ B1v,
    const void* __restrict__ B2v,
    float* __restrict__ outMN,
    __hip_bfloat16* __restrict__ qbuf, __hip_bfloat16* __restrict__ kbuf,
    __hip_bfloat16* __restrict__ vT,
    const float* __restrict__ rc, const float* __restrict__ rs)
{
    __shared__ union {
        struct { unsigned short A[128][40]; unsigned short B[128][40]; } s;
        unsigned short CtV[128][136];
        unsigned short CtR[128][137];
    } sm;

    const int m0 = blockIdx.x * 128;
    const int by = blockIdx.y;

    int widx = 0, hh = 0, n0 = 0;
    const void* Bv;
    if (MODE == 1) {
        widx = by >> 4; hh = by & 15; n0 = hh * 128;
        Bv = (widx == 0) ? B0v : (widx == 1) ? B1v : B2v;
    } else { n0 = by * 128; Bv = B0v; }

    const int t = threadIdx.x, lane = t & 63, w = t >> 6;
    const int l15 = lane & 15, g4 = lane >> 4, koff = g4 * 8;
    const int mw = (w >> 1) * 64, nw = (w & 1) * 64;
    const int srow = t >> 1, scol = (t & 1) * 16;

    const floatx4 z = {0.f, 0.f, 0.f, 0.f};
    floatx4 acc[4][4];
    #pragma unroll
    for (int i = 0; i < 4; i++)
        #pragma unroll
        for (int j = 0; j < 4; j++) acc[i][j] = z;

    const int K = EMB;
    for (int k0 = 0; k0 < K; k0 += 32) {
        ushort8 a0, a1, b0, b1;
        if (MODE == 0) {
            const unsigned short* Ab = (const unsigned short*)Av;
            a0 = *(const ushort8*)(Ab + (size_t)(m0 + srow) * K + k0 + scol);
            a1 = *(const ushort8*)(Ab + (size_t)(m0 + srow) * K + k0 + scol + 8);
        } else {
            const float* Af = (const float*)Av;
            const float* ap = Af + (size_t)(m0 + srow) * K + k0 + scol;
            a0 = cvt16_lo(*(const float4*)(ap),     *(const float4*)(ap + 4));
            a1 = cvt16_lo(*(const float4*)(ap + 8), *(const float4*)(ap + 12));
        }
        {
            const float* Bf = (const float*)Bv;
            const float* bp = Bf + (size_t)(n0 + srow) * K + k0 + scol;
            b0 = cvt16_lo(*(const float4*)(bp),     *(const float4*)(bp + 4));
            b1 = cvt16_lo(*(const float4*)(bp + 8), *(const float4*)(bp + 12));
        }
        __syncthreads();
        *(ushort8*)&sm.s.A[srow][scol]     = a0;
        *(ushort8*)&sm.s.A[srow][scol + 8] = a1;
        *(ushort8*)&sm.s.B[srow][scol]     = b0;
        *(ushort8*)&sm.s.B[srow][scol + 8] = b1;
        __syncthreads();

        bf16x8 af[4], bg[4];
        #pragma unroll
        for (int i = 0; i < 4; i++)
            af[i] = *(const bf16x8*)&sm.s.A[mw + i * 16 + l15][koff];
        #pragma unroll
        for (int j = 0; j < 4; j++)
            bg[j] = *(const bf16x8*)&sm.s.B[nw + j * 16 + l15][koff];
        #pragma unroll
        for (int i = 0; i < 4; i++)
            #pragma unroll
            for (int j = 0; j < 4; j++)
                acc[i][j] = __builtin_amdgcn_mfma_f32_16x16x32_bf16(af[i], bg[j], acc[i][j], 0, 0, 0);
    }

    if (MODE == 0) {
        #pragma unroll
        for (int i = 0; i < 4; i++)
            #pragma unroll
            for (int j = 0; j < 4; j++)
                #pragma unroll
                for (int r = 0; r < 4; r++) {
                    int row = m0 + mw + i * 16 + g4 * 4 + r;
                    int col = n0 + nw + j * 16 + l15;
                    outMN[(size_t)row * EMB + col] = acc[i][j][r];
                }
    } else if (widx < 2) {
        __syncthreads();
        #pragma unroll
        for (int i = 0; i < 4; i++)
            #pragma unroll
            for (int j = 0; j < 4; j++)
                #pragma unroll
                for (int r = 0; r < 4; r++)
                    sm.CtR[nw + j * 16 + l15][mw + i * 16 + g4 * 4 + r] = f2b(acc[i][j][r]);
        __syncthreads();
        __hip_bfloat16* dst = (widx == 0) ? qbuf : kbuf;
        const int dd = t & 127, sl0 = t >> 7;
        #pragma unroll 4
        for (int rep = 0; rep < 64; rep++) {
            const int sl = rep * 2 + sl0;
            const int s  = m0 + sl;
            const float c  = rc[(size_t)s * HD + dd];
            const float sn = rs[(size_t)s * HD + dd];
            const float x0 = b2f(sm.CtR[dd][sl]);
            const float xr = b2f(sm.CtR[dd ^ 64][sl]);
            const float rot = (dd < 64) ? -xr : xr;
            dst[((size_t)hh * S_LEN + s) * HD + dd] = __float2bfloat16(x0 * c + rot * sn);
        }
    } else {
        __syncthreads();
        #pragma unroll
        for (int i = 0; i < 4; i++)
            #pragma unroll
            for (int j = 0; j < 4; j++)
                #pragma unroll
                for (int r = 0; r < 4; r++)
                    sm.CtV[nw + j * 16 + l15][mw + i * 16 + g4 * 4 + r] = f2b(acc[i][j][r]);
        __syncthreads();
        const int dd = t >> 1, ms = (t & 1) * 64;
        __hip_bfloat16* dstv = vT + ((size_t)hh * HD + dd) * S_LEN + m0 + ms;
        #pragma unroll
        for (int c = 0; c < 8; c++)
            *(ushort8*)(dstv + c * 8) = *(const ushort8*)&sm.CtV[dd][ms + c * 8];
    }
}

// ---- fallback flash (non-split) --------------------------------------------
__global__ __launch_bounds__(256) void flash_attn(
    const __hip_bfloat16* __restrict__ qb, const __hip_bfloat16* __restrict__ kb,
    const __hip_bfloat16* __restrict__ vT, __hip_bfloat16* __restrict__ attnb)
{
    __shared__ __align__(16) unsigned short Ks[64][136];
    __shared__ __align__(16) unsigned short Vs[128][72];
    __shared__ __align__(16) unsigned short Ps[4][16][72];

    const int bx = (gridDim.x - 1) - blockIdx.x;
    const int q0 = bx * 64;
    const int h  = blockIdx.y;
    const int t    = threadIdx.x;
    const int lane = t & 63;
    const int w    = t >> 6;
    const size_t hb  = (size_t)h * S_LEN;
    const size_t hbT = (size_t)h * HD;

    const int l15 = lane & 15;
    const int g4  = lane >> 4;
    const int koff = g4 * 8;

    const int kr = t >> 2;
    const int kc = (t & 3) * 32;
    const int vr = t >> 1;
    const int vc = (t & 1) * 32;

    bf16x8 qf[4];
    const __hip_bfloat16* qrow = qb + (hb + q0 + w * 16 + l15) * HD;
    #pragma unroll
    for (int kk = 0; kk < 4; kk++)
        qf[kk] = *(const bf16x8*)(qrow + kk * 32 + koff);

    const floatx4 z = {0.f, 0.f, 0.f, 0.f};
    floatx4 O[8] = {z, z, z, z, z, z, z, z};
    float lpart[4] = {0.f, 0.f, 0.f, 0.f};

    const float scale = 0.08838834764831845f;

    ushort8 krg[4], vrg[4];
    {
        const __hip_bfloat16* kg = kb + (hb + kr) * HD + kc;
        const __hip_bfloat16* vg = vT + (hbT + vr) * S_LEN + vc;
        #pragma unroll
        for (int c = 0; c < 4; c++) krg[c] = *(const ushort8*)(kg + c * 8);
        #pragma unroll
        for (int c = 0; c < 4; c++) vrg[c] = *(const ushort8*)(vg + c * 8);
    }

    for (int jb0 = 0; jb0 <= q0; jb0 += 64) {
        __syncthreads();
        #pragma unroll
        for (int c = 0; c < 4; c++) *(ushort8*)&Ks[kr][kc + c * 8] = krg[c];
        #pragma unroll
        for (int c = 0; c < 4; c++) *(ushort8*)&Vs[vr][vc + c * 8] = vrg[c];
        __syncthreads();

        if (jb0 + 64 <= q0) {
            const __hip_bfloat16* kg = kb + (hb + jb0 + 64 + kr) * HD + kc;
            const __hip_bfloat16* vg = vT + (hbT + vr) * S_LEN + jb0 + 64 + vc;
            #pragma unroll
            for (int c = 0; c < 4; c++) krg[c] = *(const ushort8*)(kg + c * 8);
            #pragma unroll
            for (int c = 0; c < 4; c++) vrg[c] = *(const ushort8*)(vg + c * 8);
        }

        floatx4 sc[4];
        #pragma unroll
        for (int jb = 0; jb < 4; jb++) {
            floatx4 acc = z;
            #pragma unroll
            for (int kk = 0; kk < 4; kk++) {
                bf16x8 kf = *(const bf16x8*)&Ks[jb * 16 + l15][kk * 32 + koff];
                acc = __builtin_amdgcn_mfma_f32_16x16x32_bf16(qf[kk], kf, acc, 0, 0, 0);
            }
            sc[jb] = acc;
        }

        const bool diag = (jb0 == q0);
        #pragma unroll
        for (int jb = 0; jb < 4; jb++)
            #pragma unroll
            for (int r = 0; r < 4; r++) {
                float s = sc[jb][r] * scale;
                if (diag && (jb * 16 + l15) > (w * 16 + g4 * 4 + r)) s = -1e30f;
                float p = __expf(s - 6.0f);
                sc[jb][r] = p;
                lpart[r] += p;
            }

        #pragma unroll
        for (int jb = 0; jb < 4; jb++)
            #pragma unroll
            for (int r = 0; r < 4; r++)
                Ps[w][g4 * 4 + r][jb * 16 + l15] = f2b(sc[jb][r]);

        #pragma unroll
        for (int half = 0; half < 2; half++) {
            bf16x8 af = *(const bf16x8*)&Ps[w][l15][half * 32 + koff];
            #pragma unroll
            for (int db = 0; db < 8; db++) {
                bf16x8 bf = *(const bf16x8*)&Vs[db * 16 + l15][half * 32 + koff];
                O[db] = __builtin_amdgcn_mfma_f32_16x16x32_bf16(af, bf, O[db], 0, 0, 0);
            }
        }
    }

    float inv[4];
    #pragma unroll
    for (int r = 0; r < 4; r++) {
        float s = lpart[r];
        #pragma unroll
        for (int o = 1; o < 16; o <<= 1) s += __shfl_xor(s, o, 64);
        inv[r] = 1.f / s;
    }

    #pragma unroll
    for (int db = 0; db < 8; db++)
        #pragma unroll
        for (int r = 0; r < 4; r++) {
            const int row = q0 + w * 16 + g4 * 4 + r;
            const int col = h * HD + db * 16 + l15;
            attnb[(size_t)row * EMB + col] = __float2bfloat16(O[db][r] * inv[r]);
        }
}

// ---- launch ---------------------------------------------------------------
extern "C" void kernel_launch(void* const* d_in, const int* in_sizes, int n_in,
                              void* d_out, int out_size, void* d_ws, size_t ws_size,
                              hipStream_t stream) {
    const float* x  = (const float*)d_in[0];
    const float* rc = (const float*)d_in[1];
    const float* rs = (const float*)d_in[2];
    const float* Wq = (const float*)d_in[3];
    const float* Wk = (const float*)d_in[4];
    const float* Wv = (const float*)d_in[5];
    const float* Wo = (const float*)d_in[6];
    float* out = (float*)d_out;

    const size_t MB = 1u << 20;
    char* ws = (char*)d_ws;
    __hip_bfloat16* qbuf  = (__hip_bfloat16*)(ws);            // (h,s,d)  8 MB
    __hip_bfloat16* kbuf  = (__hip_bfloat16*)(ws +  8 * MB);  // (h,s,d)  8 MB
    __hip_bfloat16* vTbuf = (__hip_bfloat16*)(ws + 16 * MB);  // (h,d,s)  8 MB
    __hip_bfloat16* attnb = (__hip_bfloat16*)(ws + 24 * MB);  // (s,h*d)  8 MB

    const bool pre = (ws_size >= 72 * MB);

    if (pre) {
        unsigned short* xb  = (unsigned short*)(ws + 32 * MB);
        unsigned short* wqb = (unsigned short*)(ws + 40 * MB);
        unsigned short* wkb = (unsigned short*)(ws + 48 * MB);
        unsigned short* wvb = (unsigned short*)(ws + 56 * MB);
        unsigned short* wob = (unsigned short*)(ws + 64 * MB);
        // regions reused AFTER the QKV GEMM (xb/wqb/wkb are dead by then):
        unsigned short* Op0 = xb;                                // 8 MB
        unsigned short* Op1 = wqb;                               // 8 MB
        float*          lp0 = (float*)wkb;                       // 128 KB
        float*          lp1 = (float*)(ws + 48 * MB + 256 * 1024);

        hipLaunchKernelGGL(cvt_bf16x5, dim3(4096, 5), dim3(256), 0, stream,
                           x, Wq, Wk, Wv, Wo, xb, wqb, wkb, wvb, wob);

        hipLaunchKernelGGL(gemm_qkv_async, dim3(16, 48), dim3(256), 0, stream,
                           xb, wqb, wkb, wvb, qbuf, kbuf, vTbuf, rc, rs);

        hipLaunchKernelGGL(flash_attn_sk, dim3(S_LEN / 64, NH, 2), dim3(256), 0, stream,
                           qbuf, kbuf, vTbuf, Op0, Op1, lp0, lp1);

        hipLaunchKernelGGL(attn_combine, dim3(2048), dim3(256), 0, stream,
                           Op0, Op1, lp0, lp1, attnb);

        hipLaunchKernelGGL(gemm_wo_async, dim3(16, 32), dim3(256), 0, stream,
                           (const unsigned short*)attnb, wob, out);
    } else {
        hipLaunchKernelGGL((gemm128f<1>), dim3(16, 48), dim3(256), 0, stream,
                           (const void*)x, (const void*)Wq, (const void*)Wk,
                           (const void*)Wv, (float*)nullptr,
                           qbuf, kbuf, vTbuf, rc, rs);

        hipLaunchKernelGGL(flash_attn, dim3(S_LEN / 64, NH), dim3(256), 0, stream,
                           qbuf, kbuf, vTbuf, attnb);

        hipLaunchKernelGGL((gemm128f<0>), dim3(16, 16), dim3(256), 0, stream,
                           (const void*)attnb, (const void*)Wo, (const void*)nullptr,
                           (const void*)nullptr, out,
                           (__hip_bfloat16*)nullptr, (__hip_bfloat16*)nullptr,
                           (__hip_bfloat16*)nullptr, rc, rs);
    }
}